// Round 6
// baseline (228.254 us; speedup 1.0000x reference)
//
#include <hip/hip_runtime.h>

typedef __attribute__((ext_vector_type(8))) short short8;
typedef __attribute__((ext_vector_type(4))) float f32x4;
typedef unsigned short u16;
typedef unsigned int u32;

// b=16, C=256, n=4096(64x64), HEADS=4, D=32, hidden=128, O3=384
// Inputs fp32, output fp32. Internal bf16 MFMA.

__device__ __forceinline__ u16 f2bf(float f) {
    u32 x = __float_as_uint(f);
    u32 r = (x + 0x7fffu + ((x >> 16) & 1u)) >> 16;
    return (u16)r;
}
__device__ __forceinline__ float bf2f(u16 v) {
    union { u32 i; float f; } u; u.i = ((u32)v) << 16; return u.f;
}

// ---------------- K1: qkv GEMM, 128x128 tile, fused x-transpose + W-convert ----------------
// grid (mt=3, nt=32, b=16), mt innermost for L2 reuse of the x tile.
// mt=0 -> qT[b][n][e] (D[e][n], pack 4 e)    mt=1 -> kbuf[b][o][n], mt=2 -> vbuf (D[n][o], pack 4 n)
__global__ __launch_bounds__(256) void k_qkv(const float* __restrict__ x,
                                             const float* __restrict__ W,
                                             u16* __restrict__ qT,
                                             u16* __restrict__ kbuf,
                                             u16* __restrict__ vbuf) {
    __shared__ alignas(16) u16 sA[128 * 72];   // W tile [o_local][c]
    __shared__ alignas(16) u16 sB[128 * 72];   // x tile [n_local][c] (transposed in staging)
    int t = threadIdx.x;
    int mt = blockIdx.x, n0 = blockIdx.y * 128, b = blockIdx.z;
    int m0 = mt * 128;
    int lane = t & 63, wv = t >> 6, l16 = lane & 15, lq = lane >> 4;
    int wr = wv >> 1, wc = wv & 1;
    int tr = t >> 3, tl = t & 7;

    f32x4 acc[4][4];
#pragma unroll
    for (int i = 0; i < 4; i++)
#pragma unroll
        for (int j = 0; j < 4; j++) acc[i][j] = (f32x4){0.f, 0.f, 0.f, 0.f};

    for (int kc = 0; kc < 4; kc++) {
        __syncthreads();
        // stage A: W fp32 [m0+row][kc*64+c] -> sA[row][c] bf16
#pragma unroll
        for (int i = 0; i < 4; i++) {
            int row = i * 32 + tr;
#pragma unroll
            for (int jj = 0; jj < 2; jj++) {
                int c = (tl + jj * 8) * 4;
                float4 v = *reinterpret_cast<const float4*>(W + (size_t)(m0 + row) * 256 + kc * 64 + c);
                u32 w0 = (u32)f2bf(v.x) | ((u32)f2bf(v.y) << 16);
                u32 w1 = (u32)f2bf(v.z) | ((u32)f2bf(v.w) << 16);
                uint2 o = {w0, w1};
                *reinterpret_cast<uint2*>(&sA[row * 72 + c]) = o;
            }
        }
        // stage B: x fp32 [kc*64+cl][n0+n] -> sB[n][cl] bf16 (transpose)
#pragma unroll
        for (int i = 0; i < 2; i++) {
            int cl = i * 32 + tr;
#pragma unroll
            for (int jj = 0; jj < 4; jj++) {
                int n = (tl + jj * 8) * 4;
                float4 v = *reinterpret_cast<const float4*>(x + (size_t)(b * 256 + kc * 64 + cl) * 4096 + n0 + n);
                sB[(n + 0) * 72 + cl] = f2bf(v.x);
                sB[(n + 1) * 72 + cl] = f2bf(v.y);
                sB[(n + 2) * 72 + cl] = f2bf(v.z);
                sB[(n + 3) * 72 + cl] = f2bf(v.w);
            }
        }
        __syncthreads();
#pragma unroll
        for (int ks = 0; ks < 2; ks++) {
            int col = ks * 32 + lq * 8;
            short8 af[4], bf[4];
#pragma unroll
            for (int i = 0; i < 4; i++)
                af[i] = *reinterpret_cast<const short8*>(&sA[(wr * 64 + i * 16 + l16) * 72 + col]);
#pragma unroll
            for (int j = 0; j < 4; j++)
                bf[j] = *reinterpret_cast<const short8*>(&sB[(wc * 64 + j * 16 + l16) * 72 + col]);
            if (mt == 0) {
#pragma unroll
                for (int i = 0; i < 4; i++)
#pragma unroll
                    for (int j = 0; j < 4; j++)
                        acc[i][j] = __builtin_amdgcn_mfma_f32_16x16x32_bf16(af[i], bf[j], acc[i][j], 0, 0, 0);
            } else {
#pragma unroll
                for (int i = 0; i < 4; i++)
#pragma unroll
                    for (int j = 0; j < 4; j++)
                        acc[i][j] = __builtin_amdgcn_mfma_f32_16x16x32_bf16(bf[j], af[i], acc[i][j], 0, 0, 0);
            }
        }
    }
    if (mt == 0) {
        // D[e][n]: row=lq*4+rr -> e, col=l16 -> n; pack 4 consecutive e
#pragma unroll
        for (int i = 0; i < 4; i++) {
            int ebase = wr * 64 + i * 16 + lq * 4;
#pragma unroll
            for (int j = 0; j < 4; j++) {
                int n = n0 + wc * 64 + j * 16 + l16;
                f32x4 a = acc[i][j];
                u32 w0 = (u32)f2bf(a[0]) | ((u32)f2bf(a[1]) << 16);
                u32 w1 = (u32)f2bf(a[2]) | ((u32)f2bf(a[3]) << 16);
                uint2 o = {w0, w1};
                *reinterpret_cast<uint2*>(qT + (size_t)(b * 4096 + n) * 128 + ebase) = o;
            }
        }
    } else {
        // D[n][o]: row=lq*4+rr -> n, col=l16 -> o; pack 4 consecutive n
        u16* dst = (mt == 1) ? kbuf : vbuf;
#pragma unroll
        for (int i = 0; i < 4; i++) {
            int o = wr * 64 + i * 16 + l16;
#pragma unroll
            for (int j = 0; j < 4; j++) {
                int nb4 = n0 + wc * 64 + j * 16 + lq * 4;
                f32x4 a = acc[i][j];
                u32 w0 = (u32)f2bf(a[0]) | ((u32)f2bf(a[1]) << 16);
                u32 w1 = (u32)f2bf(a[2]) | ((u32)f2bf(a[3]) << 16);
                uint2 ov = {w0, w1};
                *reinterpret_cast<uint2*>(dst + (size_t)(b * 128 + o) * 4096 + nb4) = ov;
            }
        }
    }
}

// ---------------- K2: P = exp(k) in-place + per-row sum (no max pass: |k| <~ 2) ----------------
__global__ __launch_bounds__(256) void k_exp(u16* __restrict__ kbuf,
                                             float* __restrict__ rowsum) {
    __shared__ float red[4];
    int bi = blockIdx.x;
    u16* row = kbuf + (size_t)bi * 4096;
    int t = threadIdx.x;
    float s = 0.f;
#pragma unroll
    for (int i = 0; i < 2; i++) {
        uint4 v = *reinterpret_cast<const uint4*>(row + (t + i * 256) * 8);
        u32 w[4] = {v.x, v.y, v.z, v.w};
#pragma unroll
        for (int j = 0; j < 4; j++) {
            float e0 = __expf(__uint_as_float(w[j] << 16));
            float e1 = __expf(__uint_as_float(w[j] & 0xffff0000u));
            u16 b0 = f2bf(e0), b1 = f2bf(e1);
            s += bf2f(b0) + bf2f(b1);      // sum what the MFMA will actually see
            w[j] = (u32)b0 | ((u32)b1 << 16);
        }
        uint4 ov = {w[0], w[1], w[2], w[3]};
        *reinterpret_cast<uint4*>(row + (t + i * 256) * 8) = ov;
    }
#pragma unroll
    for (int off = 32; off > 0; off >>= 1) s += __shfl_down(s, off, 64);
    int wv = t >> 6;
    if ((t & 63) == 0) red[wv] = s;
    __syncthreads();
    if (t == 0) rowsum[bi] = red[0] + red[1] + red[2] + red[3];
}

// ---------------- K3: context partials via MFMA: part = P(32xN) * V(32xN)^T ----------------
__global__ __launch_bounds__(256) void k_ctx(const u16* __restrict__ pbuf,
                                             const u16* __restrict__ vbuf,
                                             float* __restrict__ part) {
    __shared__ float sred[4][32][32];
    int s = blockIdx.x, h = blockIdx.y, b = blockIdx.z;
    int t = threadIdx.x;
    int lane = t & 63, wv = t >> 6, l16 = lane & 15, lq = lane >> 4;
    const u16* Pb = pbuf + (size_t)(b * 128 + h * 32) * 4096;
    const u16* Vb = vbuf + (size_t)(b * 128 + h * 32) * 4096;
    int nb = s * 512 + wv * 128;

    f32x4 acc[2][2];
#pragma unroll
    for (int i = 0; i < 2; i++)
#pragma unroll
        for (int j = 0; j < 2; j++) acc[i][j] = (f32x4){0.f, 0.f, 0.f, 0.f};

#pragma unroll
    for (int kk = 0; kk < 4; kk++) {
        int col = nb + kk * 32 + lq * 8;
        short8 af[2], bf[2];
#pragma unroll
        for (int i = 0; i < 2; i++)
            af[i] = *reinterpret_cast<const short8*>(Pb + (size_t)(i * 16 + l16) * 4096 + col);
#pragma unroll
        for (int j = 0; j < 2; j++)
            bf[j] = *reinterpret_cast<const short8*>(Vb + (size_t)(j * 16 + l16) * 4096 + col);
#pragma unroll
        for (int i = 0; i < 2; i++)
#pragma unroll
            for (int j = 0; j < 2; j++)
                acc[i][j] = __builtin_amdgcn_mfma_f32_16x16x32_bf16(af[i], bf[j], acc[i][j], 0, 0, 0);
    }
#pragma unroll
    for (int i = 0; i < 2; i++)
#pragma unroll
        for (int j = 0; j < 2; j++)
#pragma unroll
            for (int rr = 0; rr < 4; rr++)
                sred[wv][i * 16 + lq * 4 + rr][j * 16 + l16] = acc[i][j][rr];
    __syncthreads();
    int de0 = t * 4;
    const float* s0 = &sred[0][0][0];
    f32x4 sum;
#pragma unroll
    for (int q = 0; q < 4; q++)
        sum[q] = s0[de0 + q] + s0[1024 + de0 + q] + s0[2048 + de0 + q] + s0[3072 + de0 + q];
    int bh = b * 4 + h;
    *reinterpret_cast<f32x4*>(part + (size_t)(bh * 8 + s) * 1024 + de0) = sum;
}

// ---------------- K4: reduce partials, normalize rows by 1/rowsum, M = Wout x ctx_bd ----------------
__global__ __launch_bounds__(256) void k_Mred(const float* __restrict__ part,
                                              const float* __restrict__ rowsum,
                                              const float* __restrict__ Wout,
                                              u16* __restrict__ Mb) {
    __shared__ float sc[4096];
    int b = blockIdx.x, t = threadIdx.x;
#pragma unroll
    for (int it = 0; it < 16; it++) {
        int idx = it * 256 + t;          // h*1024 + d*32 + e
        int h = idx >> 10, de = idx & 1023, d = de >> 5;
        float s = 0.f;
#pragma unroll
        for (int p = 0; p < 8; p++) s += part[(size_t)((b * 4 + h) * 8 + p) * 1024 + de];
        float rs = rowsum[b * 128 + h * 32 + d];
        sc[idx] = s / rs;
    }
    __syncthreads();
    int o = t;
#pragma unroll
    for (int h = 0; h < 4; h++) {
        float wvv[32];
#pragma unroll
        for (int d = 0; d < 32; d++) wvv[d] = Wout[o * 128 + h * 32 + d];
        for (int e = 0; e < 32; e++) {
            float a = 0.f;
#pragma unroll
            for (int d = 0; d < 32; d++) a += wvv[d] * sc[h * 1024 + d * 32 + e];
            Mb[(b * 256 + o) * 128 + h * 32 + e] = f2bf(a);
        }
    }
}

// ---------------- K5: y = M x qT^T + bias, 128x128 tile, float4 stores ----------------
// grid (mt=2, nt=32, b=16). Operands swapped -> D[n][o], lane holds 4 consecutive n.
__global__ __launch_bounds__(256) void k_y(const u16* __restrict__ Mb,
                                           const u16* __restrict__ qT,
                                           const float* __restrict__ bout,
                                           float* __restrict__ y) {
    __shared__ alignas(16) u16 sA[128 * 72];
    __shared__ alignas(16) u16 sB[128 * 72];
    int t = threadIdx.x;
    int mt = blockIdx.x, n0 = blockIdx.y * 128, b = blockIdx.z;
    int m0 = mt * 128;
    int lane = t & 63, wv = t >> 6, l16 = lane & 15, lq = lane >> 4;
    int wr = wv >> 1, wc = wv & 1;
    int r = t >> 3, c8 = (t & 7) * 8;

    f32x4 acc[4][4];
#pragma unroll
    for (int i = 0; i < 4; i++)
#pragma unroll
        for (int j = 0; j < 4; j++) acc[i][j] = (f32x4){0.f, 0.f, 0.f, 0.f};

    for (int kc = 0; kc < 2; kc++) {
        __syncthreads();
#pragma unroll
        for (int i = 0; i < 4; i++) {
            int row = i * 32 + r;
            *reinterpret_cast<uint4*>(&sA[row * 72 + c8]) =
                *reinterpret_cast<const uint4*>(Mb + (size_t)(b * 256 + m0 + row) * 128 + kc * 64 + c8);
            *reinterpret_cast<uint4*>(&sB[row * 72 + c8]) =
                *reinterpret_cast<const uint4*>(qT + (size_t)(b * 4096 + n0 + row) * 128 + kc * 64 + c8);
        }
        __syncthreads();
#pragma unroll
        for (int ks = 0; ks < 2; ks++) {
            int col = ks * 32 + lq * 8;
            short8 af[4], bf[4];
#pragma unroll
            for (int i = 0; i < 4; i++)
                af[i] = *reinterpret_cast<const short8*>(&sA[(wr * 64 + i * 16 + l16) * 72 + col]);
#pragma unroll
            for (int j = 0; j < 4; j++)
                bf[j] = *reinterpret_cast<const short8*>(&sB[(wc * 64 + j * 16 + l16) * 72 + col]);
#pragma unroll
            for (int i = 0; i < 4; i++)
#pragma unroll
                for (int j = 0; j < 4; j++)
                    acc[i][j] = __builtin_amdgcn_mfma_f32_16x16x32_bf16(bf[j], af[i], acc[i][j], 0, 0, 0);
        }
    }
    // D[n][o]: row=lq*4+rr -> n, col=l16 -> o
#pragma unroll
    for (int i = 0; i < 4; i++) {
        int o = m0 + wr * 64 + i * 16 + l16;
        float bias = bout[o];
        float* yrow = y + (size_t)(b * 256 + o) * 4096;
#pragma unroll
        for (int j = 0; j < 4; j++) {
            int nb4 = n0 + wc * 64 + j * 16 + lq * 4;
            f32x4 a = acc[i][j];
            float4 ov = {a[0] + bias, a[1] + bias, a[2] + bias, a[3] + bias};
            *reinterpret_cast<float4*>(yrow + nb4) = ov;
        }
    }
}

extern "C" void kernel_launch(void* const* d_in, const int* in_sizes, int n_in,
                              void* d_out, int out_size, void* d_ws, size_t ws_size,
                              hipStream_t stream) {
    const float* x    = (const float*)d_in[0];
    const float* Wqkv = (const float*)d_in[1];
    const float* Wout = (const float*)d_in[2];
    const float* bout = (const float*)d_in[3];
    float* y = (float*)d_out;

    char* ws = (char*)d_ws;
    u16*   qT     = (u16*)(ws);                   // 16 MB
    u16*   kb     = (u16*)(ws + 16777216);        // 16 MB (exp in-place -> P)
    u16*   vb     = (u16*)(ws + 33554432);        // 16 MB
    float* part   = (float*)(ws + 50331648);      // 2 MB
    u16*   Mb     = (u16*)(ws + 52428800);        // 1 MB
    float* rowsum = (float*)(ws + 53477376);      // 8 KB

    k_qkv<<<dim3(3, 32, 16), 256, 0, stream>>>(x, Wqkv, qT, kb, vb);
    k_exp<<<2048, 256, 0, stream>>>(kb, rowsum);
    k_ctx<<<dim3(8, 4, 16), 256, 0, stream>>>(kb, vb, part);
    k_Mred<<<16, 256, 0, stream>>>(part, rowsum, Wout, Mb);
    k_y<<<dim3(2, 32, 16), 256, 0, stream>>>(Mb, qT, bout, y);
}